// Round 1
// baseline (1574.707 us; speedup 1.0000x reference)
//
#include <hip/hip_runtime.h>
#include <hip/hip_bf16.h>
#include <hip/hip_fp16.h>

// RNN: INPUT=128, HIDDEN=256, OUTPUT=128, BATCH=64, SEQ=2048
// ref: xp[s,b,h] = sum_i x[b,s,i]*W_ih[h,i] + b_ih[h] + b_hh[h]
//      h = tanh(xp_t + h @ W_hh^T)   (scan over s)
//      out = h_T @ W_fc^T + b_fc

#define S_LEN 2048
#define B_SZ  64
#define IN_D  128
#define HID   256
#define OUT_D 128

typedef _Float16 half2_t __attribute__((ext_vector_type(2)));
typedef _Float16 half8_t __attribute__((ext_vector_type(8)));
typedef float    f32x4   __attribute__((ext_vector_type(4)));

#if __has_builtin(__builtin_amdgcn_fdot2)
#define FDOT2(a, b, c) __builtin_amdgcn_fdot2((a), (b), (c), false)
#else
#define FDOT2(a, b, c) ((c) + (float)(a).x * (float)(b).x + (float)(a).y * (float)(b).y)
#endif

#if __has_builtin(__builtin_amdgcn_exp2f)
#define EXP2F(x) __builtin_amdgcn_exp2f(x)
#else
#define EXP2F(x) exp2f(x)
#endif

// ---------------- Kernel A: xp = x @ W_ih^T + b_ih + b_hh  (f16 out to ws) ---
// grid (2048, 16), block 256 (4 waves). wave handles one 16x16 output tile,
// K=128 via 4x mfma_f32_16x16x32_f16.
// A-frag layout: lane l -> row (l&15), k = (l>>4)*8 + e (8 consecutive f16)
// B-frag layout: lane l -> col (l&15), k = (l>>4)*8 + e
// C/D layout (verified): col = lane&15, row = (lane>>4)*4 + reg
__global__ __launch_bounds__(256) void xproj_kernel(
    const float* __restrict__ x, const float* __restrict__ W_ih,
    const float* __restrict__ b_ih, const float* __restrict__ b_hh,
    _Float16* __restrict__ xp)
{
    const int lane = threadIdx.x & 63;
    const int wave = threadIdx.x >> 6;
    const int m0 = (blockIdx.x * 4 + wave) * 16;   // x-row tile (b*2048+s)
    const int n0 = blockIdx.y * 16;                // hidden tile
    const int idx16 = lane & 15;
    const int kq = lane >> 4;                      // 0..3

    f32x4 acc = {0.f, 0.f, 0.f, 0.f};

    #pragma unroll
    for (int sl = 0; sl < 4; ++sl) {
        const int koff = sl * 32 + kq * 8;
        const float4* ap = (const float4*)(x + (size_t)(m0 + idx16) * IN_D + koff);
        float4 a0 = ap[0], a1 = ap[1];
        const float4* bp = (const float4*)(W_ih + (size_t)(n0 + idx16) * IN_D + koff);
        float4 b0 = bp[0], b1 = bp[1];
        half8_t af = {(_Float16)a0.x, (_Float16)a0.y, (_Float16)a0.z, (_Float16)a0.w,
                      (_Float16)a1.x, (_Float16)a1.y, (_Float16)a1.z, (_Float16)a1.w};
        half8_t bf = {(_Float16)b0.x, (_Float16)b0.y, (_Float16)b0.z, (_Float16)b0.w,
                      (_Float16)b1.x, (_Float16)b1.y, (_Float16)b1.z, (_Float16)b1.w};
        acc = __builtin_amdgcn_mfma_f32_16x16x32_f16(af, bf, acc, 0, 0, 0);
    }

    const float bias = b_ih[n0 + idx16] + b_hh[n0 + idx16];
    #pragma unroll
    for (int r = 0; r < 4; ++r) {
        const int m = m0 + kq * 4 + r;            // = b*2048 + s
        const int bb = m >> 11;
        const int ss = m & 2047;
        xp[((size_t)ss * B_SZ + bb) * HID + n0 + idx16] = (_Float16)(acc[r] + bias);
    }
}

// ---------------- Kernel B: sequential recurrence + final FC ----------------
// 64 blocks (one per batch row), 256 threads (one per hidden unit j).
// Thread j holds W_hh[j][0:256] as 128 packed-f16 half2 in VGPRs.
// h double-buffered in LDS (f16); one barrier per step.
// per step: 32 broadcast ds_read_b128 + 128 v_dot2_f32_f16 + tanh.
__global__ __launch_bounds__(256) void rnn_kernel(
    const _Float16* __restrict__ xp, const float* __restrict__ W_hh,
    const float* __restrict__ W_fc, const float* __restrict__ b_fc,
    float* __restrict__ out)
{
    const int b = blockIdx.x;
    const int j = threadIdx.x;

    __shared__ __align__(16) _Float16 hbuf[2][HID];

    // preload W_hh row j -> 128 half2 registers (static unrolled indexing)
    half2_t w[128];
    {
        const float4* wr = (const float4*)(W_hh + (size_t)j * HID);
        #pragma unroll
        for (int c = 0; c < 64; ++c) {
            float4 v = wr[c];
            w[2 * c]     = half2_t{(_Float16)v.x, (_Float16)v.y};
            w[2 * c + 1] = half2_t{(_Float16)v.z, (_Float16)v.w};
        }
    }

    hbuf[0][j] = (_Float16)0.f;

    const _Float16* xpb = xp + (size_t)b * HID + j;   // stride B_SZ*HID per step
    _Float16 p0 = xpb[0];
    _Float16 p1 = xpb[(size_t)B_SZ * HID];

    __syncthreads();

    for (int t = 0; t < S_LEN; ++t) {
        const int rb = t & 1;
        float acc = 0.f;
        const float4* hp = (const float4*)hbuf[rb];
        #pragma unroll
        for (int c = 0; c < 32; ++c) {
            float4 hv = hp[c];
            union { float f; half2_t h; } u0, u1, u2, u3;
            u0.f = hv.x; u1.f = hv.y; u2.f = hv.z; u3.f = hv.w;
            acc = FDOT2(w[4 * c + 0], u0.h, acc);
            acc = FDOT2(w[4 * c + 1], u1.h, acc);
            acc = FDOT2(w[4 * c + 2], u2.h, acc);
            acc = FDOT2(w[4 * c + 3], u3.h, acc);
        }

        const float xv = (float)p0;
        p0 = p1;
        if (t + 2 < S_LEN) p1 = xpb[(size_t)(t + 2) * B_SZ * HID];

        const float z = acc + xv;
        // tanh(z) = 1 - 2/(exp2(z*2*log2e)+1); handles +-inf saturation correctly
        const float e = EXP2F(z * 2.8853900817779268f);
        const float th = 1.f - 2.f / (e + 1.f);

        hbuf[rb ^ 1][j] = (_Float16)th;
        __syncthreads();
    }

    // final FC: out[b][o] = sum_j h[j]*W_fc[o][j] + b_fc[o]
    // h_final lives in hbuf[0] (t=2047 wrote rb^1 = 0)
    if (j < OUT_D) {
        float acc2 = b_fc[j];
        const float4* wp = (const float4*)(W_fc + (size_t)j * HID);
        const _Float16* hf = hbuf[0];
        #pragma unroll 8
        for (int c = 0; c < 64; ++c) {
            float4 wv = wp[c];
            acc2 += wv.x * (float)hf[4 * c + 0] + wv.y * (float)hf[4 * c + 1] +
                    wv.z * (float)hf[4 * c + 2] + wv.w * (float)hf[4 * c + 3];
        }
        out[(size_t)b * OUT_D + j] = acc2;
    }
}

extern "C" void kernel_launch(void* const* d_in, const int* in_sizes, int n_in,
                              void* d_out, int out_size, void* d_ws, size_t ws_size,
                              hipStream_t stream) {
    const float* x    = (const float*)d_in[0];
    const float* W_ih = (const float*)d_in[1];
    const float* W_hh = (const float*)d_in[2];
    const float* b_ih = (const float*)d_in[3];
    const float* b_hh = (const float*)d_in[4];
    const float* W_fc = (const float*)d_in[5];
    const float* b_fc = (const float*)d_in[6];
    float* outp = (float*)d_out;

    _Float16* xp_ws = (_Float16*)d_ws;   // needs 2048*64*256*2 = 64 MiB

    dim3 gA(S_LEN * B_SZ / 64, HID / 16, 1);   // (2048, 16)
    xproj_kernel<<<gA, 256, 0, stream>>>(x, W_ih, b_ih, b_hh, xp_ws);

    rnn_kernel<<<B_SZ, HID, 0, stream>>>(xp_ws, W_hh, W_fc, b_fc, outp);
}

// Round 2
// 1387.042 us; speedup vs baseline: 1.1353x; 1.1353x over previous
//
#include <hip/hip_runtime.h>
#include <hip/hip_bf16.h>
#include <hip/hip_fp16.h>

// RNN: INPUT=128, HIDDEN=256, OUTPUT=128, BATCH=64, SEQ=2048
// ref: xp[b,s,h] = sum_i x[b,s,i]*W_ih[h,i] + b_ih[h] + b_hh[h]
//      h = tanh(xp_t + h @ W_hh^T)   (scan over s)
//      out = h_T @ W_fc^T + b_fc

#define S_LEN 2048
#define B_SZ  64
#define IN_D  128
#define HID   256
#define OUT_D 128

typedef _Float16 half2_t __attribute__((ext_vector_type(2)));
typedef _Float16 half8_t __attribute__((ext_vector_type(8)));
typedef float    f32x4   __attribute__((ext_vector_type(4)));

#if __has_builtin(__builtin_amdgcn_fdot2)
#define FDOT2(a, b, c) __builtin_amdgcn_fdot2((a), (b), (c), false)
#else
#define FDOT2(a, b, c) ((c) + (float)(a).x * (float)(b).x + (float)(a).y * (float)(b).y)
#endif

#if __has_builtin(__builtin_amdgcn_exp2f)
#define EXP2F(x) __builtin_amdgcn_exp2f(x)
#else
#define EXP2F(x) exp2f(x)
#endif

// ---------------- Kernel A: xp = x @ W_ih^T + b_ih + b_hh  (f16 out to ws) ---
// grid (2048), block 256 (4 waves). Block handles 64 consecutive m-rows
// (m = b*2048+s); wave w takes rows m0+w*16 .. +16. A-fragments (x tile,
// K=128) are loaded ONCE per wave and reused across all 16 hidden 16-col
// chunks -> x is fetched exactly once (64 MB), W_ih (128 KB f32) L2-hits.
// xp layout: [m][h] = [b][s][h], f16.
// A-frag: lane l -> row (l&15), k = (l>>4)*8 + e  (8 consecutive f16)
// B-frag: lane l -> col (l&15), same k pattern
// C/D:    col = lane&15, row = (lane>>4)*4 + reg   (verified layout)
__global__ __launch_bounds__(256) void xproj_kernel(
    const float* __restrict__ x, const float* __restrict__ W_ih,
    const float* __restrict__ b_ih, const float* __restrict__ b_hh,
    _Float16* __restrict__ xp)
{
    const int lane  = threadIdx.x & 63;
    const int wave  = threadIdx.x >> 6;
    const int r0    = blockIdx.x * 64 + wave * 16;   // row tile base (m)
    const int idx16 = lane & 15;
    const int kq    = lane >> 4;                     // 0..3

    // load A fragments once: 4 k-slices of 32
    half8_t afr[4];
    #pragma unroll
    for (int sl = 0; sl < 4; ++sl) {
        const float4* ap = (const float4*)(x + (size_t)(r0 + idx16) * IN_D + sl * 32 + kq * 8);
        float4 a0 = ap[0], a1 = ap[1];
        afr[sl] = half8_t{(_Float16)a0.x, (_Float16)a0.y, (_Float16)a0.z, (_Float16)a0.w,
                          (_Float16)a1.x, (_Float16)a1.y, (_Float16)a1.z, (_Float16)a1.w};
    }

    // loop over 16 hidden-column chunks
    #pragma unroll 2
    for (int nc = 0; nc < 16; ++nc) {
        const int n0 = nc * 16;
        f32x4 acc = {0.f, 0.f, 0.f, 0.f};
        #pragma unroll
        for (int sl = 0; sl < 4; ++sl) {
            const float4* bp = (const float4*)(W_ih + (size_t)(n0 + idx16) * IN_D + sl * 32 + kq * 8);
            float4 b0 = bp[0], b1 = bp[1];
            half8_t bf = {(_Float16)b0.x, (_Float16)b0.y, (_Float16)b0.z, (_Float16)b0.w,
                          (_Float16)b1.x, (_Float16)b1.y, (_Float16)b1.z, (_Float16)b1.w};
            acc = __builtin_amdgcn_mfma_f32_16x16x32_f16(afr[sl], bf, acc, 0, 0, 0);
        }
        const float bias = b_ih[n0 + idx16] + b_hh[n0 + idx16];
        #pragma unroll
        for (int r = 0; r < 4; ++r) {
            const int m = r0 + kq * 4 + r;
            xp[(size_t)m * HID + n0 + idx16] = (_Float16)(acc[r] + bias);
        }
    }
}

// ---------------- Kernel B: sequential recurrence + final FC ----------------
// 64 blocks (one per batch row), 256 threads (one per hidden unit j).
// Thread j holds W_hh[j][0:256] as 128 packed-f16 half2 in VGPRs.
// h double-buffered in LDS (f16); one barrier per step.
// 4 parallel accumulators: dep-chain 32x~6cyc (hidden under 256-cyc dot2
// issue stream) instead of 128x~8.
__global__ __launch_bounds__(256) void rnn_kernel(
    const _Float16* __restrict__ xp, const float* __restrict__ W_hh,
    const float* __restrict__ W_fc, const float* __restrict__ b_fc,
    float* __restrict__ out)
{
    const int b = blockIdx.x;
    const int j = threadIdx.x;

    __shared__ __align__(16) _Float16 hbuf[2][HID];

    // preload W_hh row j -> 128 half2 registers (static unrolled indexing)
    half2_t w[128];
    {
        const float4* wr = (const float4*)(W_hh + (size_t)j * HID);
        #pragma unroll
        for (int c = 0; c < 64; ++c) {
            float4 v = wr[c];
            w[2 * c]     = half2_t{(_Float16)v.x, (_Float16)v.y};
            w[2 * c + 1] = half2_t{(_Float16)v.z, (_Float16)v.w};
        }
    }

    hbuf[0][j] = (_Float16)0.f;

    // xp layout [b][s][h]: contiguous 512B per step for this block
    const _Float16* xpb = xp + (size_t)b * S_LEN * HID + j;
    _Float16 p0 = xpb[0];
    _Float16 p1 = xpb[HID];

    __syncthreads();

    for (int t = 0; t < S_LEN; ++t) {
        const int rb = t & 1;
        float a0 = 0.f, a1 = 0.f, a2 = 0.f, a3 = 0.f;
        const float4* hp = (const float4*)hbuf[rb];
        #pragma unroll
        for (int c = 0; c < 32; ++c) {
            float4 hv = hp[c];
            union { float f; half2_t h; } u0, u1, u2, u3;
            u0.f = hv.x; u1.f = hv.y; u2.f = hv.z; u3.f = hv.w;
            a0 = FDOT2(w[4 * c + 0], u0.h, a0);
            a1 = FDOT2(w[4 * c + 1], u1.h, a1);
            a2 = FDOT2(w[4 * c + 2], u2.h, a2);
            a3 = FDOT2(w[4 * c + 3], u3.h, a3);
        }
        const float acc = (a0 + a1) + (a2 + a3);

        const float xv = (float)p0;
        p0 = p1;
        const int tn = (t + 2 < S_LEN) ? (t + 2) : (S_LEN - 1);
        p1 = xpb[(size_t)tn * HID];

        const float z = acc + xv;
        // tanh(z) = 1 - 2/(exp2(z*2*log2e)+1); saturates correctly at +-inf
        const float e = EXP2F(z * 2.8853900817779268f);
        const float th = 1.f - 2.f / (e + 1.f);

        hbuf[rb ^ 1][j] = (_Float16)th;
        __syncthreads();
    }

    // final FC: out[b][o] = sum_j h[j]*W_fc[o][j] + b_fc[o]
    // h_final lives in hbuf[0] (t=2047 wrote rb^1 = 0)
    if (j < OUT_D) {
        float acc2 = b_fc[j];
        const float4* wp = (const float4*)(W_fc + (size_t)j * HID);
        const _Float16* hf = hbuf[0];
        #pragma unroll 8
        for (int c = 0; c < 64; ++c) {
            float4 wv = wp[c];
            acc2 += wv.x * (float)hf[4 * c + 0] + wv.y * (float)hf[4 * c + 1] +
                    wv.z * (float)hf[4 * c + 2] + wv.w * (float)hf[4 * c + 3];
        }
        out[(size_t)b * OUT_D + j] = acc2;
    }
}

extern "C" void kernel_launch(void* const* d_in, const int* in_sizes, int n_in,
                              void* d_out, int out_size, void* d_ws, size_t ws_size,
                              hipStream_t stream) {
    const float* x    = (const float*)d_in[0];
    const float* W_ih = (const float*)d_in[1];
    const float* W_hh = (const float*)d_in[2];
    const float* b_ih = (const float*)d_in[3];
    const float* b_hh = (const float*)d_in[4];
    const float* W_fc = (const float*)d_in[5];
    const float* b_fc = (const float*)d_in[6];
    float* outp = (float*)d_out;

    _Float16* xp_ws = (_Float16*)d_ws;   // needs 2048*64*256*2 = 64 MiB

    dim3 gA(S_LEN * B_SZ / 64, 1, 1);   // 2048 blocks x 64 rows
    xproj_kernel<<<gA, 256, 0, stream>>>(x, W_ih, b_ih, b_hh, xp_ws);

    rnn_kernel<<<B_SZ, HID, 0, stream>>>(xp_ws, W_hh, W_fc, b_fc, outp);
}

// Round 3
// 1377.222 us; speedup vs baseline: 1.1434x; 1.0071x over previous
//
#include <hip/hip_runtime.h>
#include <hip/hip_bf16.h>
#include <hip/hip_fp16.h>

// RNN: INPUT=128, HIDDEN=256, OUTPUT=128, BATCH=64, SEQ=2048
// ref: xp[b,s,h] = sum_i x[b,s,i]*W_ih[h,i] + b_ih[h] + b_hh[h]
//      h = tanh(xp_t + h @ W_hh^T)   (scan over s)
//      out = h_T @ W_fc^T + b_fc

#define S_LEN 2048
#define B_SZ  64
#define IN_D  128
#define HID   256
#define OUT_D 128

typedef _Float16 half2_t __attribute__((ext_vector_type(2)));
typedef _Float16 half8_t __attribute__((ext_vector_type(8)));
typedef float    f32x4   __attribute__((ext_vector_type(4)));

#if __has_builtin(__builtin_amdgcn_fdot2)
#define FDOT2(a, b, c) __builtin_amdgcn_fdot2((a), (b), (c), false)
#else
#define FDOT2(a, b, c) ((c) + (float)(a).x * (float)(b).x + (float)(a).y * (float)(b).y)
#endif

#if __has_builtin(__builtin_amdgcn_exp2f)
#define EXP2F(x) __builtin_amdgcn_exp2f(x)
#else
#define EXP2F(x) exp2f(x)
#endif

// ---------------- Kernel A: xp = x @ W_ih^T + b_ih + b_hh  (f16 out to ws) ---
// grid (2048), block 256 (4 waves). Block handles 64 consecutive m-rows
// (m = b*2048+s); wave w takes rows m0+w*16 .. +16. A-fragments (x tile,
// K=128) loaded ONCE per wave, reused across 16 hidden 16-col chunks.
// xp layout: [m][h] = [b][s][h], f16.
__global__ __launch_bounds__(256) void xproj_kernel(
    const float* __restrict__ x, const float* __restrict__ W_ih,
    const float* __restrict__ b_ih, const float* __restrict__ b_hh,
    _Float16* __restrict__ xp)
{
    const int lane  = threadIdx.x & 63;
    const int wave  = threadIdx.x >> 6;
    const int r0    = blockIdx.x * 64 + wave * 16;   // row tile base (m)
    const int idx16 = lane & 15;
    const int kq    = lane >> 4;                     // 0..3

    // load A fragments once: 4 k-slices of 32
    half8_t afr[4];
    #pragma unroll
    for (int sl = 0; sl < 4; ++sl) {
        const float4* ap = (const float4*)(x + (size_t)(r0 + idx16) * IN_D + sl * 32 + kq * 8);
        float4 a0 = ap[0], a1 = ap[1];
        afr[sl] = half8_t{(_Float16)a0.x, (_Float16)a0.y, (_Float16)a0.z, (_Float16)a0.w,
                          (_Float16)a1.x, (_Float16)a1.y, (_Float16)a1.z, (_Float16)a1.w};
    }

    // loop over 16 hidden-column chunks
    #pragma unroll 2
    for (int nc = 0; nc < 16; ++nc) {
        const int n0 = nc * 16;
        f32x4 acc = {0.f, 0.f, 0.f, 0.f};
        #pragma unroll
        for (int sl = 0; sl < 4; ++sl) {
            const float4* bp = (const float4*)(W_ih + (size_t)(n0 + idx16) * IN_D + sl * 32 + kq * 8);
            float4 b0 = bp[0], b1 = bp[1];
            half8_t bf = {(_Float16)b0.x, (_Float16)b0.y, (_Float16)b0.z, (_Float16)b0.w,
                          (_Float16)b1.x, (_Float16)b1.y, (_Float16)b1.z, (_Float16)b1.w};
            acc = __builtin_amdgcn_mfma_f32_16x16x32_f16(afr[sl], bf, acc, 0, 0, 0);
        }
        const float bias = b_ih[n0 + idx16] + b_hh[n0 + idx16];
        #pragma unroll
        for (int r = 0; r < 4; ++r) {
            const int m = r0 + kq * 4 + r;
            xp[(size_t)m * HID + n0 + idx16] = (_Float16)(acc[r] + bias);
        }
    }
}

// ---------------- Kernel B: sequential recurrence + final FC ----------------
// 64 blocks (one per batch row), 256 threads (one per hidden unit j).
// Thread j holds W_hh[j][0:256] as 128 packed-f16 half2 in VGPRs.
// __launch_bounds__(256,1): we run exactly 1 wave/SIMD (64 blocks on 64 CUs),
// so allow the register allocator up to the full budget — the w[128] array
// MUST stay in VGPRs (round-2 kernel had VGPR_Count=100 < 128: compiler
// rematerialized weight loads from L2 every step = the main stall).
// asm keep-alive after preload makes w[] opaque defs (cannot remat).
__global__ __launch_bounds__(256, 1) void rnn_kernel(
    const _Float16* __restrict__ xp, const float* __restrict__ W_hh,
    const float* __restrict__ W_fc, const float* __restrict__ b_fc,
    float* __restrict__ out)
{
    const int b = blockIdx.x;
    const int j = threadIdx.x;

    __shared__ __align__(16) _Float16 hbuf[2][HID];

    // preload W_hh row j -> 128 half2 registers
    half2_t w[128];
    {
        const float4* wr = (const float4*)(W_hh + (size_t)j * HID);
        #pragma unroll
        for (int c = 0; c < 64; ++c) {
            float4 v = wr[c];
            w[2 * c]     = half2_t{(_Float16)v.x, (_Float16)v.y};
            w[2 * c + 1] = half2_t{(_Float16)v.z, (_Float16)v.w};
        }
    }
    // force-register-resident: opaque definition, compiler cannot re-load
    #pragma unroll
    for (int c = 0; c < 128; ++c) {
        asm volatile("" : "+v"(w[c]));
    }

    hbuf[0][j] = (_Float16)0.f;

    // xp layout [b][s][h]: contiguous 512B per step for this block
    const _Float16* xpb = xp + (size_t)b * S_LEN * HID + j;
    _Float16 p0 = xpb[0];
    _Float16 p1 = xpb[HID];

    __syncthreads();

    for (int t = 0; t < S_LEN; ++t) {
        const int rb = t & 1;
        float a0 = 0.f, a1 = 0.f, a2 = 0.f, a3 = 0.f;
        const float4* hp = (const float4*)hbuf[rb];
        #pragma unroll
        for (int c = 0; c < 32; ++c) {
            float4 hv = hp[c];
            union { float f; half2_t h; } u0, u1, u2, u3;
            u0.f = hv.x; u1.f = hv.y; u2.f = hv.z; u3.f = hv.w;
            a0 = FDOT2(w[4 * c + 0], u0.h, a0);
            a1 = FDOT2(w[4 * c + 1], u1.h, a1);
            a2 = FDOT2(w[4 * c + 2], u2.h, a2);
            a3 = FDOT2(w[4 * c + 3], u3.h, a3);
        }
        const float acc = (a0 + a1) + (a2 + a3);

        const float xv = (float)p0;
        p0 = p1;
        const int tn = (t + 2 < S_LEN) ? (t + 2) : (S_LEN - 1);
        p1 = xpb[(size_t)tn * HID];

        const float z = acc + xv;
        // tanh(z) = 1 - 2/(exp2(z*2*log2e)+1); saturates correctly at +-inf
        const float e = EXP2F(z * 2.8853900817779268f);
        const float th = 1.f - 2.f / (e + 1.f);

        hbuf[rb ^ 1][j] = (_Float16)th;
        __syncthreads();
    }

    // final FC: out[b][o] = sum_j h[j]*W_fc[o][j] + b_fc[o]
    // h_final lives in hbuf[0] (t=2047 wrote rb^1 = 0)
    if (j < OUT_D) {
        float acc2 = b_fc[j];
        const float4* wp = (const float4*)(W_fc + (size_t)j * HID);
        const _Float16* hf = hbuf[0];
        #pragma unroll 8
        for (int c = 0; c < 64; ++c) {
            float4 wv = wp[c];
            acc2 += wv.x * (float)hf[4 * c + 0] + wv.y * (float)hf[4 * c + 1] +
                    wv.z * (float)hf[4 * c + 2] + wv.w * (float)hf[4 * c + 3];
        }
        out[(size_t)b * OUT_D + j] = acc2;
    }
}

extern "C" void kernel_launch(void* const* d_in, const int* in_sizes, int n_in,
                              void* d_out, int out_size, void* d_ws, size_t ws_size,
                              hipStream_t stream) {
    const float* x    = (const float*)d_in[0];
    const float* W_ih = (const float*)d_in[1];
    const float* W_hh = (const float*)d_in[2];
    const float* b_ih = (const float*)d_in[3];
    const float* b_hh = (const float*)d_in[4];
    const float* W_fc = (const float*)d_in[5];
    const float* b_fc = (const float*)d_in[6];
    float* outp = (float*)d_out;

    _Float16* xp_ws = (_Float16*)d_ws;   // needs 2048*64*256*2 = 64 MiB

    dim3 gA(S_LEN * B_SZ / 64, 1, 1);   // 2048 blocks x 64 rows
    xproj_kernel<<<gA, 256, 0, stream>>>(x, W_ih, b_ih, b_hh, xp_ws);

    rnn_kernel<<<B_SZ, HID, 0, stream>>>(xp_ws, W_hh, W_fc, b_fc, outp);
}